// Round 15
// baseline (448.049 us; speedup 1.0000x reference)
//
#include <hip/hip_runtime.h>

typedef _Float16 f16;
typedef _Float16 f16x2 __attribute__((ext_vector_type(2)));
typedef _Float16 f16x4 __attribute__((ext_vector_type(4)));
typedef _Float16 f16x8 __attribute__((ext_vector_type(8)));
typedef float    f32x2 __attribute__((ext_vector_type(2)));
typedef float    f32x4 __attribute__((ext_vector_type(4)));
typedef short    s16x4 __attribute__((ext_vector_type(4)));
typedef short    s16x8 __attribute__((ext_vector_type(8)));

// async global->LDS, 16B per lane; LDS dest = wave-uniform base + lane*16
#define GLDS16(gptr, lptr)                                                     \
  __builtin_amdgcn_global_load_lds(                                            \
      (const __attribute__((address_space(1))) void*)(gptr),                   \
      (__attribute__((address_space(3))) void*)(lptr), 16, 0, 0)

#define S_BARRIER() __builtin_amdgcn_s_barrier()
#define FENCE() asm volatile("" ::: "memory")
#define WAIT_VM0() asm volatile("s_waitcnt vmcnt(0)" ::: "memory")
#define WAIT_LGKM0() asm volatile("s_waitcnt lgkmcnt(0)" ::: "memory")
#define SETPRIO(x) __builtin_amdgcn_s_setprio(x)

__device__ inline short f32_to_bf16_rne(float f) {
  unsigned u = __builtin_bit_cast(unsigned, f);
  return (short)((u + 0x7FFFu + ((u >> 16) & 1u)) >> 16);
}

// ---------------- fused fp32 -> f16 cast of x, w_qkv, w_proj ----------------
__global__ __launch_bounds__(256) void k_cast3(const float* __restrict__ a,
                                               const float* __restrict__ b,
                                               const float* __restrict__ c,
                                               f16* __restrict__ oa,
                                               f16* __restrict__ ob,
                                               f16* __restrict__ oc) {
  int i = blockIdx.x * 256 + threadIdx.x;  // [0, 2097152)
  const float* src;
  f16* dst;
  int off;
  if (i < 1048576) { src = a; dst = oa; off = i; }
  else if (i < 1835008) { src = b; dst = ob; off = i - 1048576; }
  else { src = c; dst = oc; off = i - 1835008; }
  f32x4 v = ((const f32x4*)src)[off];
  f16x4 h;
  h[0] = (f16)v[0]; h[1] = (f16)v[1]; h[2] = (f16)v[2]; h[3] = (f16)v[3];
  ((f16x4*)dst)[off] = h;
}

// ---------------- GEMM1 fused: qkv = x@w^T, epilogue does RoPE+split+Vt ------
// Round-5 loop = measured optimum (r11 retile +15.6, r12 A-to-reg +7.7,
// r13 full-dbuf +3, r18 XCD swizzle +5 -- all regressed). DO NOT TOUCH.
// V epilogue (r17): vt stored in K=32 PV-FRAGMENT ORDER:
//   vt[((((bh*16+jcc)*16 + d*4 + mp)*64 + lq8*16 + lrv)*8 + j0 + r]
//   = V^T[d*16+lrv][jcc*128 + mp*32 + lq8*8 + j0 + r]   (bf16)
__global__ __launch_bounds__(256, 4) void k_gemm_qkv(
    const f16* __restrict__ A, const f16* __restrict__ B,
    const float* __restrict__ rope, f16* __restrict__ qh,
    f16* __restrict__ kh, short* __restrict__ vt) {
  const int K = 1024;
  __shared__ f16 sA[128 * 64];
  __shared__ f16 sB[128 * 64];
  const int tid = threadIdx.x;
  const int wave = tid >> 6, lane = tid & 63;
  const int lr = lane & 15, lq = lane >> 4;
  const int lr7 = lr & 7;
  const int wm = (wave >> 1) * 64, wn = (wave & 1) * 64;
  const size_t m0 = (size_t)blockIdx.x * 128, n0 = (size_t)blockIdx.y * 128;

  f32x4 acc[4][4] = {};

  const int sw8 = ((tid & 7) ^ ((tid >> 3) & 7)) * 8;
  const f16* ga = A + (m0 + (tid >> 3)) * (size_t)K + sw8;
  const f16* gb = B + (n0 + (tid >> 3)) * (size_t)K + sw8;

  for (int k0 = 0; k0 < K; k0 += 64) {
    __syncthreads();
#pragma unroll
    for (int r = 0; r < 4; ++r) {
      GLDS16(ga + (size_t)(r * 32) * K + k0, (char*)sA + r * 4096 + wave * 1024);
      GLDS16(gb + (size_t)(r * 32) * K + k0, (char*)sB + r * 4096 + wave * 1024);
    }
    __syncthreads();

#pragma unroll
    for (int kk = 0; kk < 2; ++kk) {
      f16x8 af[4], bf[4];
#pragma unroll
      for (int i = 0; i < 4; ++i)
        af[i] = *(const f16x8*)&sA[(wm + i * 16 + lr) * 64 +
                                   (((kk * 4 + lq) ^ lr7) * 8)];
#pragma unroll
      for (int j = 0; j < 4; ++j)
        bf[j] = *(const f16x8*)&sB[(wn + j * 16 + lr) * 64 +
                                   (((kk * 4 + lq) ^ lr7) * 8)];
#pragma unroll
      for (int i = 0; i < 4; ++i)
#pragma unroll
        for (int j = 0; j < 4; ++j)
          acc[i][j] = __builtin_amdgcn_mfma_f32_16x16x32_f16(af[i], bf[j],
                                                             acc[i][j], 0, 0, 0);
    }
  }

  // ---- fused epilogue (C layout: col=lane&15, row=quad*4+reg) ----
  const int region = (int)(n0 >> 10);  // 0=Q 1=K 2=V, uniform per block
  if (region == 2) {
    // V -> K=32-fragment-ordered vt (see header comment)
#pragma unroll
    for (int i = 0; i < 4; ++i)
#pragma unroll
      for (int j = 0; j < 4; ++j) {
        int e = (int)(n0 + wn + j * 16 + lr) - 2048;
        int h = e >> 6, c = e & 63;
        int d = c >> 4, lrv = c & 15;
        int m = (int)(m0 + wm + i * 16 + lq * 4);
        int b = m >> 11, t0 = m & 2047;
        int jcc = t0 >> 7, kv = t0 & 127;
        int mp = kv >> 5;           // 32-kv pair index 0..3
        int lq8 = (kv >> 3) & 3;    // target lane-high
        int j0 = kv & 7;            // 0 or 4 (kv is 4-aligned)
        s16x4 o;
#pragma unroll
        for (int r = 0; r < 4; ++r) o[r] = f32_to_bf16_rne(acc[i][j][r]);
        size_t idx =
            ((((size_t)((b * 16 + h) * 16 + jcc)) * 16 + d * 4 + mp) * 64 +
             lq8 * 16 + lrv) * 8 + j0;
        *(s16x4*)&vt[idx] = o;
      }
  } else {
    const float scl = region == 0 ? 0.1803368801111204f : 1.0f;  // 1/8*log2e
    f16* dst = region == 0 ? qh : kh;
    const int odd = lr & 1;
#pragma unroll
    for (int i = 0; i < 4; ++i)
#pragma unroll
      for (int j = 0; j < 4; ++j) {
        int e = ((int)(n0 + wn + j * 16 + lr)) & 1023;
        int h = e >> 6, c = e & 63, p = e >> 1;
        int mb = (int)(m0 + wm + i * 16 + lq * 4);
        int b = mb >> 11;
#pragma unroll
        for (int r = 0; r < 4; ++r) {
          int t = (mb + r) & 2047;
          float v = acc[i][j][r];
          float partner = __shfl_xor(v, 1);
          f32x2 cs = *(const f32x2*)&rope[((size_t)t * 512 + p) * 2];
          float out = odd ? (partner * cs[1] + v * cs[0])
                          : (v * cs[0] - partner * cs[1]);
          dst[(((size_t)(b * 16 + h)) * 2048 + t) * 64 + c] = (f16)(out * scl);
        }
      }
  }
}

// ---------------- GEMM2  C[M,N] = A[M,K]*B[N,K]^T, fp32 out, 128x128 tile ---
// ROUND-10 (kept): single-barrier double-buffer protocol.
__global__ __launch_bounds__(256, 2) void k_gemm_bt(const f16* __restrict__ A,
                                                    const f16* __restrict__ B,
                                                    float* __restrict__ C,
                                                    int M, int N, int K) {
  __shared__ f16 sA[2][128 * 64];
  __shared__ f16 sB[2][128 * 64];
  const int tid = threadIdx.x;
  const int wave = tid >> 6, lane = tid & 63;
  const int lr = lane & 15, lq = lane >> 4;
  const int lr7 = lr & 7;
  const int wm = (wave >> 1) * 64, wn = (wave & 1) * 64;
  const size_t m0 = (size_t)blockIdx.x * 128, n0 = (size_t)blockIdx.y * 128;

  f32x4 acc[4][4] = {};

  const int sw8 = ((tid & 7) ^ ((tid >> 3) & 7)) * 8;
  const f16* ga = A + (m0 + (tid >> 3)) * (size_t)K + sw8;
  const f16* gb = B + (n0 + (tid >> 3)) * (size_t)K + sw8;

  auto stage = [&](int k0, int d) {
#pragma unroll
    for (int r = 0; r < 4; ++r) {
      GLDS16(ga + (size_t)(r * 32) * K + k0,
             (char*)&sA[d][0] + r * 4096 + wave * 1024);
      GLDS16(gb + (size_t)(r * 32) * K + k0,
             (char*)&sB[d][0] + r * 4096 + wave * 1024);
    }
  };

  stage(0, 0);  // prologue prefetch

  for (int k0 = 0; k0 < K; k0 += 64) {
    const int cur = (k0 >> 6) & 1;
    WAIT_VM0();    // this K-step's stages landed
    WAIT_LGKM0();  // my previous-step LDS reads drained
    S_BARRIER();   // all waves: data resident, old reads done
    FENCE();
    if (k0 + 64 < K) stage(k0 + 64, cur ^ 1);  // prefetch under compute

#pragma unroll
    for (int kk = 0; kk < 2; ++kk) {
      f16x8 af[4], bf[4];
#pragma unroll
      for (int i = 0; i < 4; ++i)
        af[i] = *(const f16x8*)&sA[cur][(wm + i * 16 + lr) * 64 +
                                       (((kk * 4 + lq) ^ lr7) * 8)];
#pragma unroll
      for (int j = 0; j < 4; ++j)
        bf[j] = *(const f16x8*)&sB[cur][(wn + j * 16 + lr) * 64 +
                                       (((kk * 4 + lq) ^ lr7) * 8)];
#pragma unroll
      for (int i = 0; i < 4; ++i)
#pragma unroll
        for (int j = 0; j < 4; ++j)
          acc[i][j] = __builtin_amdgcn_mfma_f32_16x16x32_f16(af[i], bf[j],
                                                             acc[i][j], 0, 0, 0);
    }
  }

#pragma unroll
  for (int i = 0; i < 4; ++i)
#pragma unroll
    for (int j = 0; j < 4; ++j)
#pragma unroll
      for (int r = 0; r < 4; ++r)
        C[(m0 + wm + i * 16 + lq * 4 + r) * (size_t)N + n0 + wn + j * 16 + lr] =
            acc[i][j][r];
}

// ---------------- Flash attention (NO-max softmax, 128-q tile, kv-split) ----
// ROUND-20: single-buffered KV + 3 blocks/CU. LDS 48 KB (sQ 16 + sKV 32)
// -> 3 blocks/CU = 24 waves/CU = 6 waves/SIMD (was dbuf 80 KB, 2 blocks,
// 4/SIMD, Occ 32%). Rationale: this session's qkv evidence (r5 vs
// r11/r12/r13) -- plain {sync; stage; sync; compute} at 3 blocks/CU beat
// every dbuf variant at 2 blocks/CU; cross-block TLP covers staging
// latency better than intra-block pipelining. Per-chunk protocol is that
// verified 2-barrier pattern. Merge scratch = sKV after a rendezvous.
// r17 kept: PV at K=32 via permuted K-row staging + K=32-frag-ordered V
// (conflicts 0). r16 kv-split (4 qg x 2 kg). r19 parity-split l. setprio.
__global__ __launch_bounds__(512, 6) void k_attn(const f16* __restrict__ Qp,
                                                 const f16* __restrict__ Kp,
                                                 const short* __restrict__ Vt,
                                                 f16* __restrict__ Op) {
  __shared__ f16 sQ[128 * 64];       // 16 KB (reused as l-scratch in merge)
  __shared__ f16 sKV[16384];         // 32 KB: K 16KB + V 16KB (single buf)
  const int tid = threadIdx.x, wave = tid >> 6, lane = tid & 63;
  const int lr = lane & 15, lq = lane >> 4;
  const int lr7 = lr & 7;
  const int qg = wave & 3, kg = wave >> 2;
  const int bh = blockIdx.x, qt = blockIdx.y;
  const size_t base = (size_t)bh * 2048 * 64;

  const int sw8 = ((tid & 7) ^ ((tid >> 3) & 7)) * 8;    // K/Q granule xor

  // K staged with permuted row map (r17); V staged linearly (frag-ordered).
  auto stage_kv = [&](int jcc) {
    const f16* gk = Kp + base + (size_t)jcc * 128 * 64;
    const short* gv = Vt + (size_t)(bh * 16 + jcc) * 8192;  // frag-ordered 16KB
    char* bK = (char*)sKV;
    char* bV = bK + 16384;
#pragma unroll
    for (int r = 0; r < 2; ++r) {
      int R = r * 64 + (tid >> 3);
      int gRow = (R & ~31) |
                 ((((R >> 2) & 3) << 3) | (((R >> 4) & 1) << 2) | (R & 3));
      GLDS16(gk + (size_t)gRow * 64 + sw8, bK + r * 8192 + wave * 1024);
      GLDS16(gv + (size_t)(r * 512 + tid) * 8,   // linear copy
             bV + r * 8192 + wave * 1024);
    }
  };

  // prologue: stage Q (2 loads/thread), read q-frags
  const f16* gq = Qp + base + (size_t)qt * 128 * 64;
#pragma unroll
  for (int r = 0; r < 2; ++r)
    GLDS16(gq + (size_t)(r * 64 + (tid >> 3)) * 64 + sw8,
           (char*)sQ + r * 8192 + wave * 1024);
  WAIT_VM0();
  S_BARRIER();
  FENCE();
  const int qrow = qg * 32 + lr;  // (qg*32) % 8 == 0 -> row&7 == lr7
  f16x8 qa0 = *(const f16x8*)&sQ[qrow * 64 + ((lq ^ lr7) * 8)];
  f16x8 qa1 = *(const f16x8*)&sQ[qrow * 64 + (((4 + lq) ^ lr7) * 8)];
  f16x8 qb0 = *(const f16x8*)&sQ[(qrow + 16) * 64 + ((lq ^ lr7) * 8)];
  f16x8 qb1 = *(const f16x8*)&sQ[(qrow + 16) * 64 + (((4 + lq) ^ lr7) * 8)];

  f32x4 ota[4] = {}, otb[4] = {};
  float la0 = 0.f, la1 = 0.f, lb0 = 0.f, lb1 = 0.f;
  const int ntbase = kg * 4;  // this wave's kv-half: tiles t = kg*4 .. kg*4+3

#pragma unroll 1
  for (int jc = 0; jc < 16; ++jc) {
    WAIT_LGKM0();  // my chunk jc-1 LDS reads drained
    S_BARRIER();   // all waves done with chunk jc-1 -> buffer reusable
    FENCE();
    stage_kv(jc);  // 4 GLDS16/thread
    WAIT_VM0();    // chunk jc resident (this wave's writes)
    S_BARRIER();   // ... and everyone else's
    FENCE();

    const f16* bK = (const f16*)sKV;
    const short* bV = (const short*)((char*)sKV + 16384);

    // per 16-row tile t: S^T -> exp2 -> packed bf16; on odd t, concat the
    // tile-pair's P-frags (k=lq*8+0..7 by construction) and do K=32 PV.
    s16x4 plo_a, plo_b;
#pragma unroll
    for (int tt = 0; tt < 4; ++tt) {
      const int t = ntbase + tt;
      f16x8 kf0 = *(const f16x8*)&bK[(t * 16 + lr) * 64 + ((lq ^ lr7) * 8)];
      f16x8 kf1 =
          *(const f16x8*)&bK[(t * 16 + lr) * 64 + (((4 + lq) ^ lr7) * 8)];
      f32x4 z = {0.f, 0.f, 0.f, 0.f};
      SETPRIO(1);
      f32x4 sa = __builtin_amdgcn_mfma_f32_16x16x32_f16(kf0, qa0, z, 0, 0, 0);
      sa = __builtin_amdgcn_mfma_f32_16x16x32_f16(kf1, qa1, sa, 0, 0, 0);
      f32x4 sb = __builtin_amdgcn_mfma_f32_16x16x32_f16(kf0, qb0, z, 0, 0, 0);
      sb = __builtin_amdgcn_mfma_f32_16x16x32_f16(kf1, qb1, sb, 0, 0, 0);
      SETPRIO(0);
      s16x4 pa, pb;
#pragma unroll
      for (int r = 0; r < 4; ++r) {
        float va = __builtin_amdgcn_exp2f(sa[r]);
        float vb = __builtin_amdgcn_exp2f(sb[r]);
        if (r & 1) { la1 += va; lb1 += vb; }
        else       { la0 += va; lb0 += vb; }
        pa[r] = (short)(__builtin_bit_cast(unsigned, va) >> 16);
        pb[r] = (short)(__builtin_bit_cast(unsigned, vb) >> 16);
      }
      if ((tt & 1) == 0) {
        plo_a = pa; plo_b = pb;
      } else {
        s16x8 pa8 = {plo_a[0], plo_a[1], plo_a[2], plo_a[3],
                     pa[0], pa[1], pa[2], pa[3]};
        s16x8 pb8 = {plo_b[0], plo_b[1], plo_b[2], plo_b[3],
                     pb[0], pb[1], pb[2], pb[3]};
        const int mp = t >> 1;  // global 32-kv pair index 0..3
        SETPRIO(1);
#pragma unroll
        for (int d = 0; d < 4; ++d) {
          s16x8 vf = *(const s16x8*)&bV[((d * 4 + mp) * 64 + lane) * 8];
          ota[d] = __builtin_amdgcn_mfma_f32_16x16x32_bf16(vf, pa8, ota[d],
                                                           0, 0, 0);
          otb[d] = __builtin_amdgcn_mfma_f32_16x16x32_bf16(vf, pb8, otb[d],
                                                           0, 0, 0);
        }
        SETPRIO(0);
      }
    }
  }

  // ---- merge the two kv-halves (linear: no-max partials sum exactly) ----
  float la = la0 + la1, lb = lb0 + lb1;
  la += __shfl_xor(la, 16); la += __shfl_xor(la, 32);
  lb += __shfl_xor(lb, 16); lb += __shfl_xor(lb, 32);

  WAIT_LGKM0();  // my chunk-15 reads drained
  S_BARRIER();   // all waves done reading sKV -> reusable as scratch
  FENCE();

  float* os = (float*)((char*)sKV + qg * 8192);  // 8KB per q-group = 32KB
  float* ls = (float*)sQ;                        // l scratch
  if (kg) {
#pragma unroll
    for (int d = 0; d < 4; ++d) {
      *(f32x4*)&os[(d * 64 + lane) * 4] = ota[d];
      *(f32x4*)&os[((4 + d) * 64 + lane) * 4] = otb[d];
    }
    if (lq == 0) { ls[qg * 32 + lr] = la; ls[qg * 32 + 16 + lr] = lb; }
  }
  WAIT_LGKM0();
  S_BARRIER();
  FENCE();
  if (kg) return;

#pragma unroll
  for (int d = 0; d < 4; ++d) {
    f32x4 pa_ = *(const f32x4*)&os[(d * 64 + lane) * 4];
    f32x4 pb_ = *(const f32x4*)&os[((4 + d) * 64 + lane) * 4];
#pragma unroll
    for (int r = 0; r < 4; ++r) { ota[d][r] += pa_[r]; otb[d][r] += pb_[r]; }
  }
  la += ls[qg * 32 + lr];
  lb += ls[qg * 32 + 16 + lr];

  float rla = 1.f / la, rlb = 1.f / lb;
  int b = bh >> 4, h = bh & 15;
  int ta = qt * 128 + qg * 32 + lr;
  f16* gouta = Op + ((size_t)(b * 2048 + ta)) * 1024 + h * 64;
  f16* goutb = gouta + (size_t)16 * 1024;
#pragma unroll
  for (int d = 0; d < 4; ++d) {
    f16x4 oa, ob;
#pragma unroll
    for (int r = 0; r < 4; ++r) {
      oa[r] = (f16)(ota[d][r] * rla);
      ob[r] = (f16)(otb[d][r] * rlb);
    }
    *(f16x4*)&gouta[d * 16 + lq * 4] = oa;
    *(f16x4*)&goutb[d * 16 + lq * 4] = ob;
  }
}

// ---------------- launch ----------------
extern "C" void kernel_launch(void* const* d_in, const int* in_sizes, int n_in,
                              void* d_out, int out_size, void* d_ws,
                              size_t ws_size, hipStream_t stream) {
  const float* x     = (const float*)d_in[0];  // (2,2048,1024)
  const float* rope  = (const float*)d_in[1];  // (2048,512,2)
  const float* wqkv  = (const float*)d_in[2];  // (3072,1024)
  const float* wproj = (const float*)d_in[3];  // (1024,1024)
  float* out = (float*)d_out;                  // (2,2048,1024) fp32

  char* w = (char*)d_ws;
  const size_t MB = 1024 * 1024;
  f16* xh   = (f16*)(w + 0);        // 8 MB
  f16* wqh  = (f16*)(w + 8 * MB);   // 6 MB
  f16* wph  = (f16*)(w + 14 * MB);  // 2 MB
  f16* qh   = (f16*)(w + 16 * MB);  // 8 MB
  f16* kh   = (f16*)(w + 24 * MB);  // 8 MB
  short* vth = (short*)(w + 32 * MB); // 8 MB (bf16, K=32-fragment-ordered)
  f16* aoh  = (f16*)(w + 40 * MB);  // 8 MB  -> total 48 MB

  // all three casts in one dispatch
  k_cast3<<<8192, 256, 0, stream>>>(x, wqkv, wproj, xh, wqh, wph);

  // qkv GEMM with fused RoPE + head-split + V-fragment-store epilogue
  k_gemm_qkv<<<dim3(32, 24), 256, 0, stream>>>(xh, wqh, rope, qh, kh, vth);

  // attention -> (B,T,H*64) f16 ; 512 thr / 8 waves, kv-split, single-buf KV
  k_attn<<<dim3(32, 16), 512, 0, stream>>>(qh, kh, vth, aoh);

  // out = attn @ w_proj^T : (4096,1024) fp32
  k_gemm_bt<<<dim3(32, 8), 256, 0, stream>>>(aoh, wph, out, 4096, 1024, 1024);
}

// Round 16
// 178.454 us; speedup vs baseline: 2.5107x; 2.5107x over previous
//
#include <hip/hip_runtime.h>

typedef _Float16 f16;
typedef _Float16 f16x2 __attribute__((ext_vector_type(2)));
typedef _Float16 f16x4 __attribute__((ext_vector_type(4)));
typedef _Float16 f16x8 __attribute__((ext_vector_type(8)));
typedef float    f32x2 __attribute__((ext_vector_type(2)));
typedef float    f32x4 __attribute__((ext_vector_type(4)));
typedef short    s16x4 __attribute__((ext_vector_type(4)));
typedef short    s16x8 __attribute__((ext_vector_type(8)));

// async global->LDS, 16B per lane; LDS dest = wave-uniform base + lane*16
#define GLDS16(gptr, lptr)                                                     \
  __builtin_amdgcn_global_load_lds(                                            \
      (const __attribute__((address_space(1))) void*)(gptr),                   \
      (__attribute__((address_space(3))) void*)(lptr), 16, 0, 0)

#define S_BARRIER() __builtin_amdgcn_s_barrier()
#define FENCE() asm volatile("" ::: "memory")
#define WAIT_VM0() asm volatile("s_waitcnt vmcnt(0)" ::: "memory")
#define WAIT_LGKM0() asm volatile("s_waitcnt lgkmcnt(0)" ::: "memory")
#define SETPRIO(x) __builtin_amdgcn_s_setprio(x)

__device__ inline short f32_to_bf16_rne(float f) {
  unsigned u = __builtin_bit_cast(unsigned, f);
  return (short)((u + 0x7FFFu + ((u >> 16) & 1u)) >> 16);
}

// ---------------- fused fp32 -> f16 cast of x, w_qkv, w_proj ----------------
__global__ __launch_bounds__(256) void k_cast3(const float* __restrict__ a,
                                               const float* __restrict__ b,
                                               const float* __restrict__ c,
                                               f16* __restrict__ oa,
                                               f16* __restrict__ ob,
                                               f16* __restrict__ oc) {
  int i = blockIdx.x * 256 + threadIdx.x;  // [0, 2097152)
  const float* src;
  f16* dst;
  int off;
  if (i < 1048576) { src = a; dst = oa; off = i; }
  else if (i < 1835008) { src = b; dst = ob; off = i - 1048576; }
  else { src = c; dst = oc; off = i - 1835008; }
  f32x4 v = ((const f32x4*)src)[off];
  f16x4 h;
  h[0] = (f16)v[0]; h[1] = (f16)v[1]; h[2] = (f16)v[2]; h[3] = (f16)v[3];
  ((f16x4*)dst)[off] = h;
}

// ---------------- GEMM1 fused: qkv = x@w^T, epilogue does RoPE+split+Vt ------
// Round-5 loop = measured optimum (r11 retile +15.6, r12 A-to-reg +7.7,
// r13 full-dbuf +3, r18 XCD swizzle +5 -- all regressed). DO NOT TOUCH.
// V epilogue (r17): vt stored in K=32 PV-FRAGMENT ORDER:
//   vt[((((bh*16+jcc)*16 + d*4 + mp)*64 + lq8*16 + lrv)*8 + j0 + r]
//   = V^T[d*16+lrv][jcc*128 + mp*32 + lq8*8 + j0 + r]   (bf16)
__global__ __launch_bounds__(256, 4) void k_gemm_qkv(
    const f16* __restrict__ A, const f16* __restrict__ B,
    const float* __restrict__ rope, f16* __restrict__ qh,
    f16* __restrict__ kh, short* __restrict__ vt) {
  const int K = 1024;
  __shared__ f16 sA[128 * 64];
  __shared__ f16 sB[128 * 64];
  const int tid = threadIdx.x;
  const int wave = tid >> 6, lane = tid & 63;
  const int lr = lane & 15, lq = lane >> 4;
  const int lr7 = lr & 7;
  const int wm = (wave >> 1) * 64, wn = (wave & 1) * 64;
  const size_t m0 = (size_t)blockIdx.x * 128, n0 = (size_t)blockIdx.y * 128;

  f32x4 acc[4][4] = {};

  const int sw8 = ((tid & 7) ^ ((tid >> 3) & 7)) * 8;
  const f16* ga = A + (m0 + (tid >> 3)) * (size_t)K + sw8;
  const f16* gb = B + (n0 + (tid >> 3)) * (size_t)K + sw8;

  for (int k0 = 0; k0 < K; k0 += 64) {
    __syncthreads();
#pragma unroll
    for (int r = 0; r < 4; ++r) {
      GLDS16(ga + (size_t)(r * 32) * K + k0, (char*)sA + r * 4096 + wave * 1024);
      GLDS16(gb + (size_t)(r * 32) * K + k0, (char*)sB + r * 4096 + wave * 1024);
    }
    __syncthreads();

#pragma unroll
    for (int kk = 0; kk < 2; ++kk) {
      f16x8 af[4], bf[4];
#pragma unroll
      for (int i = 0; i < 4; ++i)
        af[i] = *(const f16x8*)&sA[(wm + i * 16 + lr) * 64 +
                                   (((kk * 4 + lq) ^ lr7) * 8)];
#pragma unroll
      for (int j = 0; j < 4; ++j)
        bf[j] = *(const f16x8*)&sB[(wn + j * 16 + lr) * 64 +
                                   (((kk * 4 + lq) ^ lr7) * 8)];
#pragma unroll
      for (int i = 0; i < 4; ++i)
#pragma unroll
        for (int j = 0; j < 4; ++j)
          acc[i][j] = __builtin_amdgcn_mfma_f32_16x16x32_f16(af[i], bf[j],
                                                             acc[i][j], 0, 0, 0);
    }
  }

  // ---- fused epilogue (C layout: col=lane&15, row=quad*4+reg) ----
  const int region = (int)(n0 >> 10);  // 0=Q 1=K 2=V, uniform per block
  if (region == 2) {
    // V -> K=32-fragment-ordered vt (see header comment)
#pragma unroll
    for (int i = 0; i < 4; ++i)
#pragma unroll
      for (int j = 0; j < 4; ++j) {
        int e = (int)(n0 + wn + j * 16 + lr) - 2048;
        int h = e >> 6, c = e & 63;
        int d = c >> 4, lrv = c & 15;
        int m = (int)(m0 + wm + i * 16 + lq * 4);
        int b = m >> 11, t0 = m & 2047;
        int jcc = t0 >> 7, kv = t0 & 127;
        int mp = kv >> 5;           // 32-kv pair index 0..3
        int lq8 = (kv >> 3) & 3;    // target lane-high
        int j0 = kv & 7;            // 0 or 4 (kv is 4-aligned)
        s16x4 o;
#pragma unroll
        for (int r = 0; r < 4; ++r) o[r] = f32_to_bf16_rne(acc[i][j][r]);
        size_t idx =
            ((((size_t)((b * 16 + h) * 16 + jcc)) * 16 + d * 4 + mp) * 64 +
             lq8 * 16 + lrv) * 8 + j0;
        *(s16x4*)&vt[idx] = o;
      }
  } else {
    const float scl = region == 0 ? 0.1803368801111204f : 1.0f;  // 1/8*log2e
    f16* dst = region == 0 ? qh : kh;
    const int odd = lr & 1;
#pragma unroll
    for (int i = 0; i < 4; ++i)
#pragma unroll
      for (int j = 0; j < 4; ++j) {
        int e = ((int)(n0 + wn + j * 16 + lr)) & 1023;
        int h = e >> 6, c = e & 63, p = e >> 1;
        int mb = (int)(m0 + wm + i * 16 + lq * 4);
        int b = mb >> 11;
#pragma unroll
        for (int r = 0; r < 4; ++r) {
          int t = (mb + r) & 2047;
          float v = acc[i][j][r];
          float partner = __shfl_xor(v, 1);
          f32x2 cs = *(const f32x2*)&rope[((size_t)t * 512 + p) * 2];
          float out = odd ? (partner * cs[1] + v * cs[0])
                          : (v * cs[0] - partner * cs[1]);
          dst[(((size_t)(b * 16 + h)) * 2048 + t) * 64 + c] = (f16)(out * scl);
        }
      }
  }
}

// ---------------- GEMM2  C[M,N] = A[M,K]*B[N,K]^T, fp32 out, 128x128 tile ---
// ROUND-10 (kept): single-barrier double-buffer protocol.
__global__ __launch_bounds__(256, 2) void k_gemm_bt(const f16* __restrict__ A,
                                                    const f16* __restrict__ B,
                                                    float* __restrict__ C,
                                                    int M, int N, int K) {
  __shared__ f16 sA[2][128 * 64];
  __shared__ f16 sB[2][128 * 64];
  const int tid = threadIdx.x;
  const int wave = tid >> 6, lane = tid & 63;
  const int lr = lane & 15, lq = lane >> 4;
  const int lr7 = lr & 7;
  const int wm = (wave >> 1) * 64, wn = (wave & 1) * 64;
  const size_t m0 = (size_t)blockIdx.x * 128, n0 = (size_t)blockIdx.y * 128;

  f32x4 acc[4][4] = {};

  const int sw8 = ((tid & 7) ^ ((tid >> 3) & 7)) * 8;
  const f16* ga = A + (m0 + (tid >> 3)) * (size_t)K + sw8;
  const f16* gb = B + (n0 + (tid >> 3)) * (size_t)K + sw8;

  auto stage = [&](int k0, int d) {
#pragma unroll
    for (int r = 0; r < 4; ++r) {
      GLDS16(ga + (size_t)(r * 32) * K + k0,
             (char*)&sA[d][0] + r * 4096 + wave * 1024);
      GLDS16(gb + (size_t)(r * 32) * K + k0,
             (char*)&sB[d][0] + r * 4096 + wave * 1024);
    }
  };

  stage(0, 0);  // prologue prefetch

  for (int k0 = 0; k0 < K; k0 += 64) {
    const int cur = (k0 >> 6) & 1;
    WAIT_VM0();    // this K-step's stages landed
    WAIT_LGKM0();  // my previous-step LDS reads drained
    S_BARRIER();   // all waves: data resident, old reads done
    FENCE();
    if (k0 + 64 < K) stage(k0 + 64, cur ^ 1);  // prefetch under compute

#pragma unroll
    for (int kk = 0; kk < 2; ++kk) {
      f16x8 af[4], bf[4];
#pragma unroll
      for (int i = 0; i < 4; ++i)
        af[i] = *(const f16x8*)&sA[cur][(wm + i * 16 + lr) * 64 +
                                       (((kk * 4 + lq) ^ lr7) * 8)];
#pragma unroll
      for (int j = 0; j < 4; ++j)
        bf[j] = *(const f16x8*)&sB[cur][(wn + j * 16 + lr) * 64 +
                                       (((kk * 4 + lq) ^ lr7) * 8)];
#pragma unroll
      for (int i = 0; i < 4; ++i)
#pragma unroll
        for (int j = 0; j < 4; ++j)
          acc[i][j] = __builtin_amdgcn_mfma_f32_16x16x32_f16(af[i], bf[j],
                                                             acc[i][j], 0, 0, 0);
    }
  }

#pragma unroll
  for (int i = 0; i < 4; ++i)
#pragma unroll
    for (int j = 0; j < 4; ++j)
#pragma unroll
      for (int r = 0; r < 4; ++r)
        C[(m0 + wm + i * 16 + lq * 4 + r) * (size_t)N + n0 + wn + j * 16 + lr] =
            acc[i][j][r];
}

// ---------------- Flash attention (NO-max softmax, 128-q tile, kv-split) ----
// ROUND-21 = ROUND-20 structure with the launch-bounds spill FIXED.
// r15's __launch_bounds__(512,6) capped VGPR at ~40 -> compiler spilled the
// ota/otb accumulators to scratch: FETCH 12.3MB->500MB, WRITE 8MB->570MB,
// attn 43->310us. (512,4) caps at 128; kernel naturally uses ~56 VGPR, so
// 48KB LDS still admits 3 blocks/CU = 6 waves/SIMD -- the occupancy
// experiment, without strangling the allocator.
// Structure: single-buffered KV (sQ 16KB + sKV 32KB = 48KB), per-chunk
// 2-barrier protocol {lgkm0; bar; stage; vm0; bar; compute} (the verified
// qkv r5 pattern); cross-block TLP covers the staging drain.
// r17 kept: PV at K=32 via permuted K-row staging + K=32-frag-ordered V
// (conflicts 0). r16 kv-split (4 qg x 2 kg). r19 parity-split l. setprio.
__global__ __launch_bounds__(512, 4) void k_attn(const f16* __restrict__ Qp,
                                                 const f16* __restrict__ Kp,
                                                 const short* __restrict__ Vt,
                                                 f16* __restrict__ Op) {
  __shared__ f16 sQ[128 * 64];       // 16 KB (reused as l-scratch in merge)
  __shared__ f16 sKV[16384];         // 32 KB: K 16KB + V 16KB (single buf)
  const int tid = threadIdx.x, wave = tid >> 6, lane = tid & 63;
  const int lr = lane & 15, lq = lane >> 4;
  const int lr7 = lr & 7;
  const int qg = wave & 3, kg = wave >> 2;
  const int bh = blockIdx.x, qt = blockIdx.y;
  const size_t base = (size_t)bh * 2048 * 64;

  const int sw8 = ((tid & 7) ^ ((tid >> 3) & 7)) * 8;    // K/Q granule xor

  // K staged with permuted row map (r17); V staged linearly (frag-ordered).
  auto stage_kv = [&](int jcc) {
    const f16* gk = Kp + base + (size_t)jcc * 128 * 64;
    const short* gv = Vt + (size_t)(bh * 16 + jcc) * 8192;  // frag-ordered 16KB
    char* bK = (char*)sKV;
    char* bV = bK + 16384;
#pragma unroll
    for (int r = 0; r < 2; ++r) {
      int R = r * 64 + (tid >> 3);
      int gRow = (R & ~31) |
                 ((((R >> 2) & 3) << 3) | (((R >> 4) & 1) << 2) | (R & 3));
      GLDS16(gk + (size_t)gRow * 64 + sw8, bK + r * 8192 + wave * 1024);
      GLDS16(gv + (size_t)(r * 512 + tid) * 8,   // linear copy
             bV + r * 8192 + wave * 1024);
    }
  };

  // prologue: stage Q (2 loads/thread), read q-frags
  const f16* gq = Qp + base + (size_t)qt * 128 * 64;
#pragma unroll
  for (int r = 0; r < 2; ++r)
    GLDS16(gq + (size_t)(r * 64 + (tid >> 3)) * 64 + sw8,
           (char*)sQ + r * 8192 + wave * 1024);
  WAIT_VM0();
  S_BARRIER();
  FENCE();
  const int qrow = qg * 32 + lr;  // (qg*32) % 8 == 0 -> row&7 == lr7
  f16x8 qa0 = *(const f16x8*)&sQ[qrow * 64 + ((lq ^ lr7) * 8)];
  f16x8 qa1 = *(const f16x8*)&sQ[qrow * 64 + (((4 + lq) ^ lr7) * 8)];
  f16x8 qb0 = *(const f16x8*)&sQ[(qrow + 16) * 64 + ((lq ^ lr7) * 8)];
  f16x8 qb1 = *(const f16x8*)&sQ[(qrow + 16) * 64 + (((4 + lq) ^ lr7) * 8)];

  f32x4 ota[4] = {}, otb[4] = {};
  float la0 = 0.f, la1 = 0.f, lb0 = 0.f, lb1 = 0.f;
  const int ntbase = kg * 4;  // this wave's kv-half: tiles t = kg*4 .. kg*4+3

#pragma unroll 1
  for (int jc = 0; jc < 16; ++jc) {
    WAIT_LGKM0();  // my chunk jc-1 LDS reads drained
    S_BARRIER();   // all waves done with chunk jc-1 -> buffer reusable
    FENCE();
    stage_kv(jc);  // 4 GLDS16/thread
    WAIT_VM0();    // chunk jc resident (this wave's writes)
    S_BARRIER();   // ... and everyone else's
    FENCE();

    const f16* bK = (const f16*)sKV;
    const short* bV = (const short*)((char*)sKV + 16384);

    // per 16-row tile t: S^T -> exp2 -> packed bf16; on odd t, concat the
    // tile-pair's P-frags (k=lq*8+0..7 by construction) and do K=32 PV.
    s16x4 plo_a, plo_b;
#pragma unroll
    for (int tt = 0; tt < 4; ++tt) {
      const int t = ntbase + tt;
      f16x8 kf0 = *(const f16x8*)&bK[(t * 16 + lr) * 64 + ((lq ^ lr7) * 8)];
      f16x8 kf1 =
          *(const f16x8*)&bK[(t * 16 + lr) * 64 + (((4 + lq) ^ lr7) * 8)];
      f32x4 z = {0.f, 0.f, 0.f, 0.f};
      SETPRIO(1);
      f32x4 sa = __builtin_amdgcn_mfma_f32_16x16x32_f16(kf0, qa0, z, 0, 0, 0);
      sa = __builtin_amdgcn_mfma_f32_16x16x32_f16(kf1, qa1, sa, 0, 0, 0);
      f32x4 sb = __builtin_amdgcn_mfma_f32_16x16x32_f16(kf0, qb0, z, 0, 0, 0);
      sb = __builtin_amdgcn_mfma_f32_16x16x32_f16(kf1, qb1, sb, 0, 0, 0);
      SETPRIO(0);
      s16x4 pa, pb;
#pragma unroll
      for (int r = 0; r < 4; ++r) {
        float va = __builtin_amdgcn_exp2f(sa[r]);
        float vb = __builtin_amdgcn_exp2f(sb[r]);
        if (r & 1) { la1 += va; lb1 += vb; }
        else       { la0 += va; lb0 += vb; }
        pa[r] = (short)(__builtin_bit_cast(unsigned, va) >> 16);
        pb[r] = (short)(__builtin_bit_cast(unsigned, vb) >> 16);
      }
      if ((tt & 1) == 0) {
        plo_a = pa; plo_b = pb;
      } else {
        s16x8 pa8 = {plo_a[0], plo_a[1], plo_a[2], plo_a[3],
                     pa[0], pa[1], pa[2], pa[3]};
        s16x8 pb8 = {plo_b[0], plo_b[1], plo_b[2], plo_b[3],
                     pb[0], pb[1], pb[2], pb[3]};
        const int mp = t >> 1;  // global 32-kv pair index 0..3
        SETPRIO(1);
#pragma unroll
        for (int d = 0; d < 4; ++d) {
          s16x8 vf = *(const s16x8*)&bV[((d * 4 + mp) * 64 + lane) * 8];
          ota[d] = __builtin_amdgcn_mfma_f32_16x16x32_bf16(vf, pa8, ota[d],
                                                           0, 0, 0);
          otb[d] = __builtin_amdgcn_mfma_f32_16x16x32_bf16(vf, pb8, otb[d],
                                                           0, 0, 0);
        }
        SETPRIO(0);
      }
    }
  }

  // ---- merge the two kv-halves (linear: no-max partials sum exactly) ----
  float la = la0 + la1, lb = lb0 + lb1;
  la += __shfl_xor(la, 16); la += __shfl_xor(la, 32);
  lb += __shfl_xor(lb, 16); lb += __shfl_xor(lb, 32);

  WAIT_LGKM0();  // my chunk-15 reads drained
  S_BARRIER();   // all waves done reading sKV -> reusable as scratch
  FENCE();

  float* os = (float*)((char*)sKV + qg * 8192);  // 8KB per q-group = 32KB
  float* ls = (float*)sQ;                        // l scratch
  if (kg) {
#pragma unroll
    for (int d = 0; d < 4; ++d) {
      *(f32x4*)&os[(d * 64 + lane) * 4] = ota[d];
      *(f32x4*)&os[((4 + d) * 64 + lane) * 4] = otb[d];
    }
    if (lq == 0) { ls[qg * 32 + lr] = la; ls[qg * 32 + 16 + lr] = lb; }
  }
  WAIT_LGKM0();
  S_BARRIER();
  FENCE();
  if (kg) return;

#pragma unroll
  for (int d = 0; d < 4; ++d) {
    f32x4 pa_ = *(const f32x4*)&os[(d * 64 + lane) * 4];
    f32x4 pb_ = *(const f32x4*)&os[((4 + d) * 64 + lane) * 4];
#pragma unroll
    for (int r = 0; r < 4; ++r) { ota[d][r] += pa_[r]; otb[d][r] += pb_[r]; }
  }
  la += ls[qg * 32 + lr];
  lb += ls[qg * 32 + 16 + lr];

  float rla = 1.f / la, rlb = 1.f / lb;
  int b = bh >> 4, h = bh & 15;
  int ta = qt * 128 + qg * 32 + lr;
  f16* gouta = Op + ((size_t)(b * 2048 + ta)) * 1024 + h * 64;
  f16* goutb = gouta + (size_t)16 * 1024;
#pragma unroll
  for (int d = 0; d < 4; ++d) {
    f16x4 oa, ob;
#pragma unroll
    for (int r = 0; r < 4; ++r) {
      oa[r] = (f16)(ota[d][r] * rla);
      ob[r] = (f16)(otb[d][r] * rlb);
    }
    *(f16x4*)&gouta[d * 16 + lq * 4] = oa;
    *(f16x4*)&goutb[d * 16 + lq * 4] = ob;
  }
}

// ---------------- launch ----------------
extern "C" void kernel_launch(void* const* d_in, const int* in_sizes, int n_in,
                              void* d_out, int out_size, void* d_ws,
                              size_t ws_size, hipStream_t stream) {
  const float* x     = (const float*)d_in[0];  // (2,2048,1024)
  const float* rope  = (const float*)d_in[1];  // (2048,512,2)
  const float* wqkv  = (const float*)d_in[2];  // (3072,1024)
  const float* wproj = (const float*)d_in[3];  // (1024,1024)
  float* out = (float*)d_out;                  // (2,2048,1024) fp32

  char* w = (char*)d_ws;
  const size_t MB = 1024 * 1024;
  f16* xh   = (f16*)(w + 0);        // 8 MB
  f16* wqh  = (f16*)(w + 8 * MB);   // 6 MB
  f16* wph  = (f16*)(w + 14 * MB);  // 2 MB
  f16* qh   = (f16*)(w + 16 * MB);  // 8 MB
  f16* kh   = (f16*)(w + 24 * MB);  // 8 MB
  short* vth = (short*)(w + 32 * MB); // 8 MB (bf16, K=32-fragment-ordered)
  f16* aoh  = (f16*)(w + 40 * MB);  // 8 MB  -> total 48 MB

  // all three casts in one dispatch
  k_cast3<<<8192, 256, 0, stream>>>(x, wqkv, wproj, xh, wqh, wph);

  // qkv GEMM with fused RoPE + head-split + V-fragment-store epilogue
  k_gemm_qkv<<<dim3(32, 24), 256, 0, stream>>>(xh, wqh, rope, qh, kh, vth);

  // attention -> (B,T,H*64) f16 ; 512 thr / 8 waves, kv-split, single-buf KV
  k_attn<<<dim3(32, 16), 512, 0, stream>>>(qh, kh, vth, aoh);

  // out = attn @ w_proj^T : (4096,1024) fp32
  k_gemm_bt<<<dim3(32, 8), 256, 0, stream>>>(aoh, wph, out, 4096, 1024, 1024);
}

// Round 17
// 175.262 us; speedup vs baseline: 2.5565x; 1.0182x over previous
//
#include <hip/hip_runtime.h>

typedef _Float16 f16;
typedef _Float16 f16x2 __attribute__((ext_vector_type(2)));
typedef _Float16 f16x4 __attribute__((ext_vector_type(4)));
typedef _Float16 f16x8 __attribute__((ext_vector_type(8)));
typedef float    f32x2 __attribute__((ext_vector_type(2)));
typedef float    f32x4 __attribute__((ext_vector_type(4)));
typedef short    s16x4 __attribute__((ext_vector_type(4)));
typedef short    s16x8 __attribute__((ext_vector_type(8)));

// async global->LDS, 16B per lane; LDS dest = wave-uniform base + lane*16
#define GLDS16(gptr, lptr)                                                     \
  __builtin_amdgcn_global_load_lds(                                            \
      (const __attribute__((address_space(1))) void*)(gptr),                   \
      (__attribute__((address_space(3))) void*)(lptr), 16, 0, 0)

#define S_BARRIER() __builtin_amdgcn_s_barrier()
#define FENCE() asm volatile("" ::: "memory")
#define WAIT_VM4() asm volatile("s_waitcnt vmcnt(4)" ::: "memory")
#define WAIT_VM0() asm volatile("s_waitcnt vmcnt(0)" ::: "memory")
#define WAIT_LGKM0() asm volatile("s_waitcnt lgkmcnt(0)" ::: "memory")
#define SETPRIO(x) __builtin_amdgcn_s_setprio(x)

__device__ inline short f32_to_bf16_rne(float f) {
  unsigned u = __builtin_bit_cast(unsigned, f);
  return (short)((u + 0x7FFFu + ((u >> 16) & 1u)) >> 16);
}

// ---------------- fused fp32 -> f16 cast of x, w_qkv, w_proj ----------------
__global__ __launch_bounds__(256) void k_cast3(const float* __restrict__ a,
                                               const float* __restrict__ b,
                                               const float* __restrict__ c,
                                               f16* __restrict__ oa,
                                               f16* __restrict__ ob,
                                               f16* __restrict__ oc) {
  int i = blockIdx.x * 256 + threadIdx.x;  // [0, 2097152)
  const float* src;
  f16* dst;
  int off;
  if (i < 1048576) { src = a; dst = oa; off = i; }
  else if (i < 1835008) { src = b; dst = ob; off = i - 1048576; }
  else { src = c; dst = oc; off = i - 1835008; }
  f32x4 v = ((const f32x4*)src)[off];
  f16x4 h;
  h[0] = (f16)v[0]; h[1] = (f16)v[1]; h[2] = (f16)v[2]; h[3] = (f16)v[3];
  ((f16x4*)dst)[off] = h;
}

// ---------------- GEMM1 fused: qkv = x@w^T, epilogue does RoPE+split+Vt ------
// Round-5 loop = measured optimum (r11 retile +15.6, r12 A-to-reg +7.7,
// r13 full-dbuf +3, r18 XCD swizzle +5 -- all regressed). DO NOT TOUCH.
// V epilogue (r17): vt stored in K=32 PV-FRAGMENT ORDER:
//   vt[((((bh*16+jcc)*16 + d*4 + mp)*64 + lq8*16 + lrv)*8 + j0 + r]
//   = V^T[d*16+lrv][jcc*128 + mp*32 + lq8*8 + j0 + r]   (bf16)
__global__ __launch_bounds__(256, 4) void k_gemm_qkv(
    const f16* __restrict__ A, const f16* __restrict__ B,
    const float* __restrict__ rope, f16* __restrict__ qh,
    f16* __restrict__ kh, short* __restrict__ vt) {
  const int K = 1024;
  __shared__ f16 sA[128 * 64];
  __shared__ f16 sB[128 * 64];
  const int tid = threadIdx.x;
  const int wave = tid >> 6, lane = tid & 63;
  const int lr = lane & 15, lq = lane >> 4;
  const int lr7 = lr & 7;
  const int wm = (wave >> 1) * 64, wn = (wave & 1) * 64;
  const size_t m0 = (size_t)blockIdx.x * 128, n0 = (size_t)blockIdx.y * 128;

  f32x4 acc[4][4] = {};

  const int sw8 = ((tid & 7) ^ ((tid >> 3) & 7)) * 8;
  const f16* ga = A + (m0 + (tid >> 3)) * (size_t)K + sw8;
  const f16* gb = B + (n0 + (tid >> 3)) * (size_t)K + sw8;

  for (int k0 = 0; k0 < K; k0 += 64) {
    __syncthreads();
#pragma unroll
    for (int r = 0; r < 4; ++r) {
      GLDS16(ga + (size_t)(r * 32) * K + k0, (char*)sA + r * 4096 + wave * 1024);
      GLDS16(gb + (size_t)(r * 32) * K + k0, (char*)sB + r * 4096 + wave * 1024);
    }
    __syncthreads();

#pragma unroll
    for (int kk = 0; kk < 2; ++kk) {
      f16x8 af[4], bf[4];
#pragma unroll
      for (int i = 0; i < 4; ++i)
        af[i] = *(const f16x8*)&sA[(wm + i * 16 + lr) * 64 +
                                   (((kk * 4 + lq) ^ lr7) * 8)];
#pragma unroll
      for (int j = 0; j < 4; ++j)
        bf[j] = *(const f16x8*)&sB[(wn + j * 16 + lr) * 64 +
                                   (((kk * 4 + lq) ^ lr7) * 8)];
#pragma unroll
      for (int i = 0; i < 4; ++i)
#pragma unroll
        for (int j = 0; j < 4; ++j)
          acc[i][j] = __builtin_amdgcn_mfma_f32_16x16x32_f16(af[i], bf[j],
                                                             acc[i][j], 0, 0, 0);
    }
  }

  // ---- fused epilogue (C layout: col=lane&15, row=quad*4+reg) ----
  const int region = (int)(n0 >> 10);  // 0=Q 1=K 2=V, uniform per block
  if (region == 2) {
    // V -> K=32-fragment-ordered vt (see header comment)
#pragma unroll
    for (int i = 0; i < 4; ++i)
#pragma unroll
      for (int j = 0; j < 4; ++j) {
        int e = (int)(n0 + wn + j * 16 + lr) - 2048;
        int h = e >> 6, c = e & 63;
        int d = c >> 4, lrv = c & 15;
        int m = (int)(m0 + wm + i * 16 + lq * 4);
        int b = m >> 11, t0 = m & 2047;
        int jcc = t0 >> 7, kv = t0 & 127;
        int mp = kv >> 5;           // 32-kv pair index 0..3
        int lq8 = (kv >> 3) & 3;    // target lane-high
        int j0 = kv & 7;            // 0 or 4 (kv is 4-aligned)
        s16x4 o;
#pragma unroll
        for (int r = 0; r < 4; ++r) o[r] = f32_to_bf16_rne(acc[i][j][r]);
        size_t idx =
            ((((size_t)((b * 16 + h) * 16 + jcc)) * 16 + d * 4 + mp) * 64 +
             lq8 * 16 + lrv) * 8 + j0;
        *(s16x4*)&vt[idx] = o;
      }
  } else {
    const float scl = region == 0 ? 0.1803368801111204f : 1.0f;  // 1/8*log2e
    f16* dst = region == 0 ? qh : kh;
    const int odd = lr & 1;
#pragma unroll
    for (int i = 0; i < 4; ++i)
#pragma unroll
      for (int j = 0; j < 4; ++j) {
        int e = ((int)(n0 + wn + j * 16 + lr)) & 1023;
        int h = e >> 6, c = e & 63, p = e >> 1;
        int mb = (int)(m0 + wm + i * 16 + lq * 4);
        int b = mb >> 11;
#pragma unroll
        for (int r = 0; r < 4; ++r) {
          int t = (mb + r) & 2047;
          float v = acc[i][j][r];
          float partner = __shfl_xor(v, 1);
          f32x2 cs = *(const f32x2*)&rope[((size_t)t * 512 + p) * 2];
          float out = odd ? (partner * cs[1] + v * cs[0])
                          : (v * cs[0] - partner * cs[1]);
          dst[(((size_t)(b * 16 + h)) * 2048 + t) * 64 + c] = (f16)(out * scl);
        }
      }
  }
}

// ---------------- GEMM2  C[M,N] = A[M,K]*B[N,K]^T, fp32 out, 128x128 tile ---
// ROUND-10 (kept): single-barrier double-buffer protocol.
__global__ __launch_bounds__(256, 2) void k_gemm_bt(const f16* __restrict__ A,
                                                    const f16* __restrict__ B,
                                                    float* __restrict__ C,
                                                    int M, int N, int K) {
  __shared__ f16 sA[2][128 * 64];
  __shared__ f16 sB[2][128 * 64];
  const int tid = threadIdx.x;
  const int wave = tid >> 6, lane = tid & 63;
  const int lr = lane & 15, lq = lane >> 4;
  const int lr7 = lr & 7;
  const int wm = (wave >> 1) * 64, wn = (wave & 1) * 64;
  const size_t m0 = (size_t)blockIdx.x * 128, n0 = (size_t)blockIdx.y * 128;

  f32x4 acc[4][4] = {};

  const int sw8 = ((tid & 7) ^ ((tid >> 3) & 7)) * 8;
  const f16* ga = A + (m0 + (tid >> 3)) * (size_t)K + sw8;
  const f16* gb = B + (n0 + (tid >> 3)) * (size_t)K + sw8;

  auto stage = [&](int k0, int d) {
#pragma unroll
    for (int r = 0; r < 4; ++r) {
      GLDS16(ga + (size_t)(r * 32) * K + k0,
             (char*)&sA[d][0] + r * 4096 + wave * 1024);
      GLDS16(gb + (size_t)(r * 32) * K + k0,
             (char*)&sB[d][0] + r * 4096 + wave * 1024);
    }
  };

  stage(0, 0);  // prologue prefetch

  for (int k0 = 0; k0 < K; k0 += 64) {
    const int cur = (k0 >> 6) & 1;
    WAIT_VM0();    // this K-step's stages landed
    WAIT_LGKM0();  // my previous-step LDS reads drained
    S_BARRIER();   // all waves: data resident, old reads done
    FENCE();
    if (k0 + 64 < K) stage(k0 + 64, cur ^ 1);  // prefetch under compute

#pragma unroll
    for (int kk = 0; kk < 2; ++kk) {
      f16x8 af[4], bf[4];
#pragma unroll
      for (int i = 0; i < 4; ++i)
        af[i] = *(const f16x8*)&sA[cur][(wm + i * 16 + lr) * 64 +
                                       (((kk * 4 + lq) ^ lr7) * 8)];
#pragma unroll
      for (int j = 0; j < 4; ++j)
        bf[j] = *(const f16x8*)&sB[cur][(wn + j * 16 + lr) * 64 +
                                       (((kk * 4 + lq) ^ lr7) * 8)];
#pragma unroll
      for (int i = 0; i < 4; ++i)
#pragma unroll
        for (int j = 0; j < 4; ++j)
          acc[i][j] = __builtin_amdgcn_mfma_f32_16x16x32_f16(af[i], bf[j],
                                                             acc[i][j], 0, 0, 0);
    }
  }

#pragma unroll
  for (int i = 0; i < 4; ++i)
#pragma unroll
    for (int j = 0; j < 4; ++j)
#pragma unroll
      for (int r = 0; r < 4; ++r)
        C[(m0 + wm + i * 16 + lq * 4 + r) * (size_t)N + n0 + wn + j * 16 + lr] =
            acc[i][j][r];
}

// ---------------- Flash attention (NO-max softmax, 128-q tile, kv-split) ----
// FINAL (r14 configuration -- best measured total, 176.2 us):
// - r17: PV at K=32 (mfma_f32_16x16x32_bf16) via permuted K-row staging
//   g(R)=(R&~31)|((R>>2)&3)<<3|((R>>4)&1)<<2|(R&3) (bijective, R&7
//   preserved) + K=32-fragment-ordered V from gemm_qkv; zero shuffles;
//   PV V-read = lane-consecutive b128, conflict-free (r10: conflicts 0).
// - r16: kv-split within block: 512 thr / 8 waves = 4 q-groups x 2
//   kv-groups; linear merge (no-max partials sum exactly).
// - r9 chunk protocol (dbuf KV, vmcnt(4) counted), r8 setprio, r19
//   parity-split l accumulators.
// Occupancy note (r16/r20/r21): grid 512 = 2 blocks/CU is the structural
// wall -- freeing LDS cannot add a 3rd block; kv-split across blocks costs
// a global merge >= the gain. (r15 lesson: never declare waves/EU beyond
// what the accumulators' VGPR budget supports -- (512,6) spilled to
// scratch, 500MB FETCH.)
__global__ __launch_bounds__(512, 4) void k_attn(const f16* __restrict__ Qp,
                                                 const f16* __restrict__ Kp,
                                                 const short* __restrict__ Vt,
                                                 f16* __restrict__ Op) {
  __shared__ f16 sQ[128 * 64];       // 16 KB (reused as l-scratch in merge)
  __shared__ f16 sKV[2 * 16384];     // 2 x (K 16KB + V 16KB) = 64 KB
  const int tid = threadIdx.x, wave = tid >> 6, lane = tid & 63;
  const int lr = lane & 15, lq = lane >> 4;
  const int lr7 = lr & 7;
  const int qg = wave & 3, kg = wave >> 2;
  const int bh = blockIdx.x, qt = blockIdx.y;
  const size_t base = (size_t)bh * 2048 * 64;

  const int sw8 = ((tid & 7) ^ ((tid >> 3) & 7)) * 8;    // K/Q granule xor

  // K staged with permuted row map (r17); V staged linearly (frag-ordered).
  auto stage_kv = [&](int jcc, int d) {
    const f16* gk = Kp + base + (size_t)jcc * 128 * 64;
    const short* gv = Vt + (size_t)(bh * 16 + jcc) * 8192;  // frag-ordered 16KB
    char* bK = (char*)sKV + d * 32768;
    char* bV = bK + 16384;
#pragma unroll
    for (int r = 0; r < 2; ++r) {
      int R = r * 64 + (tid >> 3);
      int gRow = (R & ~31) |
                 ((((R >> 2) & 3) << 3) | (((R >> 4) & 1) << 2) | (R & 3));
      GLDS16(gk + (size_t)gRow * 64 + sw8, bK + r * 8192 + wave * 1024);
      GLDS16(gv + (size_t)(r * 512 + tid) * 8,   // linear copy
             bV + r * 8192 + wave * 1024);
    }
  };

  // prologue: stage Q (2 loads/thread), then chunk0 (4 loads/thread)
  const f16* gq = Qp + base + (size_t)qt * 128 * 64;
#pragma unroll
  for (int r = 0; r < 2; ++r)
    GLDS16(gq + (size_t)(r * 64 + (tid >> 3)) * 64 + sw8,
           (char*)sQ + r * 8192 + wave * 1024);
  stage_kv(0, 0);
  WAIT_VM4();  // 6 outstanding -> retire oldest 2 (Q); chunk0 still in flight
  S_BARRIER();
  FENCE();
  const int qrow = qg * 32 + lr;  // (qg*32) % 8 == 0 -> row&7 == lr7
  f16x8 qa0 = *(const f16x8*)&sQ[qrow * 64 + ((lq ^ lr7) * 8)];
  f16x8 qa1 = *(const f16x8*)&sQ[qrow * 64 + (((4 + lq) ^ lr7) * 8)];
  f16x8 qb0 = *(const f16x8*)&sQ[(qrow + 16) * 64 + ((lq ^ lr7) * 8)];
  f16x8 qb1 = *(const f16x8*)&sQ[(qrow + 16) * 64 + (((4 + lq) ^ lr7) * 8)];

  f32x4 ota[4] = {}, otb[4] = {};
  float la0 = 0.f, la1 = 0.f, lb0 = 0.f, lb1 = 0.f;
  const int ntbase = kg * 4;  // this wave's kv-half: tiles t = kg*4 .. kg*4+3

#pragma unroll 1
  for (int jc = 0; jc < 16; ++jc) {
    const int cur = jc & 1;
    WAIT_VM0();    // chunk jc's stages (issued last iter / prologue) landed
    WAIT_LGKM0();  // my chunk jc-1 LDS reads drained
    S_BARRIER();   // rendezvous: all data resident, all old reads done
    FENCE();
    if (jc < 15) stage_kv(jc + 1, cur ^ 1);  // prefetch under full compute

    const f16* bK = (const f16*)((char*)sKV + cur * 32768);
    const short* bV = (const short*)((char*)sKV + cur * 32768 + 16384);

    // per 16-row tile t: S^T -> exp2 -> packed bf16; on odd t, concat the
    // tile-pair's P-frags (k=lq*8+0..7 by construction) and do K=32 PV.
    s16x4 plo_a, plo_b;
#pragma unroll
    for (int tt = 0; tt < 4; ++tt) {
      const int t = ntbase + tt;
      f16x8 kf0 = *(const f16x8*)&bK[(t * 16 + lr) * 64 + ((lq ^ lr7) * 8)];
      f16x8 kf1 =
          *(const f16x8*)&bK[(t * 16 + lr) * 64 + (((4 + lq) ^ lr7) * 8)];
      f32x4 z = {0.f, 0.f, 0.f, 0.f};
      SETPRIO(1);
      f32x4 sa = __builtin_amdgcn_mfma_f32_16x16x32_f16(kf0, qa0, z, 0, 0, 0);
      sa = __builtin_amdgcn_mfma_f32_16x16x32_f16(kf1, qa1, sa, 0, 0, 0);
      f32x4 sb = __builtin_amdgcn_mfma_f32_16x16x32_f16(kf0, qb0, z, 0, 0, 0);
      sb = __builtin_amdgcn_mfma_f32_16x16x32_f16(kf1, qb1, sb, 0, 0, 0);
      SETPRIO(0);
      s16x4 pa, pb;
#pragma unroll
      for (int r = 0; r < 4; ++r) {
        float va = __builtin_amdgcn_exp2f(sa[r]);
        float vb = __builtin_amdgcn_exp2f(sb[r]);
        if (r & 1) { la1 += va; lb1 += vb; }
        else       { la0 += va; lb0 += vb; }
        pa[r] = (short)(__builtin_bit_cast(unsigned, va) >> 16);
        pb[r] = (short)(__builtin_bit_cast(unsigned, vb) >> 16);
      }
      if ((tt & 1) == 0) {
        plo_a = pa; plo_b = pb;
      } else {
        s16x8 pa8 = {plo_a[0], plo_a[1], plo_a[2], plo_a[3],
                     pa[0], pa[1], pa[2], pa[3]};
        s16x8 pb8 = {plo_b[0], plo_b[1], plo_b[2], plo_b[3],
                     pb[0], pb[1], pb[2], pb[3]};
        const int mp = t >> 1;  // global 32-kv pair index 0..3
        SETPRIO(1);
#pragma unroll
        for (int d = 0; d < 4; ++d) {
          s16x8 vf = *(const s16x8*)&bV[((d * 4 + mp) * 64 + lane) * 8];
          ota[d] = __builtin_amdgcn_mfma_f32_16x16x32_bf16(vf, pa8, ota[d],
                                                           0, 0, 0);
          otb[d] = __builtin_amdgcn_mfma_f32_16x16x32_bf16(vf, pb8, otb[d],
                                                           0, 0, 0);
        }
        SETPRIO(0);
      }
    }
  }

  // ---- merge the two kv-halves (linear: no-max partials sum exactly) ----
  float la = la0 + la1, lb = lb0 + lb1;
  la += __shfl_xor(la, 16); la += __shfl_xor(la, 32);
  lb += __shfl_xor(lb, 16); lb += __shfl_xor(lb, 32);

  float* os = (float*)((char*)sKV + qg * 8192);  // 8KB per q-group, <=32KB
  float* ls = (float*)sQ;                        // l scratch
  if (kg) {
#pragma unroll
    for (int d = 0; d < 4; ++d) {
      *(f32x4*)&os[(d * 64 + lane) * 4] = ota[d];
      *(f32x4*)&os[((4 + d) * 64 + lane) * 4] = otb[d];
    }
    if (lq == 0) { ls[qg * 32 + lr] = la; ls[qg * 32 + 16 + lr] = lb; }
  }
  WAIT_LGKM0();
  S_BARRIER();
  FENCE();
  if (kg) return;

#pragma unroll
  for (int d = 0; d < 4; ++d) {
    f32x4 pa_ = *(const f32x4*)&os[(d * 64 + lane) * 4];
    f32x4 pb_ = *(const f32x4*)&os[((4 + d) * 64 + lane) * 4];
#pragma unroll
    for (int r = 0; r < 4; ++r) { ota[d][r] += pa_[r]; otb[d][r] += pb_[r]; }
  }
  la += ls[qg * 32 + lr];
  lb += ls[qg * 32 + 16 + lr];

  float rla = 1.f / la, rlb = 1.f / lb;
  int b = bh >> 4, h = bh & 15;
  int ta = qt * 128 + qg * 32 + lr;
  f16* gouta = Op + ((size_t)(b * 2048 + ta)) * 1024 + h * 64;
  f16* goutb = gouta + (size_t)16 * 1024;
#pragma unroll
  for (int d = 0; d < 4; ++d) {
    f16x4 oa, ob;
#pragma unroll
    for (int r = 0; r < 4; ++r) {
      oa[r] = (f16)(ota[d][r] * rla);
      ob[r] = (f16)(otb[d][r] * rlb);
    }
    *(f16x4*)&gouta[d * 16 + lq * 4] = oa;
    *(f16x4*)&goutb[d * 16 + lq * 4] = ob;
  }
}

// ---------------- launch ----------------
extern "C" void kernel_launch(void* const* d_in, const int* in_sizes, int n_in,
                              void* d_out, int out_size, void* d_ws,
                              size_t ws_size, hipStream_t stream) {
  const float* x     = (const float*)d_in[0];  // (2,2048,1024)
  const float* rope  = (const float*)d_in[1];  // (2048,512,2)
  const float* wqkv  = (const float*)d_in[2];  // (3072,1024)
  const float* wproj = (const float*)d_in[3];  // (1024,1024)
  float* out = (float*)d_out;                  // (2,2048,1024) fp32

  char* w = (char*)d_ws;
  const size_t MB = 1024 * 1024;
  f16* xh   = (f16*)(w + 0);        // 8 MB
  f16* wqh  = (f16*)(w + 8 * MB);   // 6 MB
  f16* wph  = (f16*)(w + 14 * MB);  // 2 MB
  f16* qh   = (f16*)(w + 16 * MB);  // 8 MB
  f16* kh   = (f16*)(w + 24 * MB);  // 8 MB
  short* vth = (short*)(w + 32 * MB); // 8 MB (bf16, K=32-fragment-ordered)
  f16* aoh  = (f16*)(w + 40 * MB);  // 8 MB  -> total 48 MB

  // all three casts in one dispatch
  k_cast3<<<8192, 256, 0, stream>>>(x, wqkv, wproj, xh, wqh, wph);

  // qkv GEMM with fused RoPE + head-split + V-fragment-store epilogue
  k_gemm_qkv<<<dim3(32, 24), 256, 0, stream>>>(xh, wqh, rope, qh, kh, vth);

  // attention -> (B,T,H*64) f16 ; 512 thr / 8 waves, kv-split, dbuf KV
  k_attn<<<dim3(32, 16), 512, 0, stream>>>(qh, kh, vth, aoh);

  // out = attn @ w_proj^T : (4096,1024) fp32
  k_gemm_bt<<<dim3(32, 8), 256, 0, stream>>>(aoh, wph, out, 4096, 1024, 1024);
}